// Round 1
// baseline (129.700 us; speedup 1.0000x reference)
//
#include <hip/hip_runtime.h>
#include <math.h>

#define IN_F   768
#define OUT_F  256
#define NROWS  8192
#define LALPHA 0.2f

// ---------------- workspace layout (floats) ----------------
// [0,     8192)   r        (row sums, atomically accumulated -> needs zero)
// [8192,  8960)   acc768   (att@X accumulator -> needs zero)
// [8960,  9728)   w1       (W @ a1)
// [9728, 10496)   w2       (W @ a2)
// [10496,18688)   s1
// [18688,26880)   s2
// [26880,35072)   att      (unnormalized exp(r - M))
// [35072,35074)   stats    {M, Z}

__device__ inline float waveReduceSum(float v) {
    for (int off = 32; off > 0; off >>= 1) v += __shfl_down(v, off, 64);
    return v;
}
__device__ inline float waveReduceMax(float v) {
    for (int off = 32; off > 0; off >>= 1) v = fmaxf(v, __shfl_down(v, off, 64));
    return v;
}

// Kernel A: w1 = W @ a[:256], w2 = W @ a[256:].  grid=3, block=256
__global__ __launch_bounds__(256) void wvec_kernel(const float* __restrict__ W,
                                                   const float* __restrict__ a,
                                                   float* __restrict__ w1,
                                                   float* __restrict__ w2) {
    __shared__ float la[2 * OUT_F];
    int tid = threadIdx.x;
    la[tid]       = a[tid];
    la[256 + tid] = a[256 + tid];
    __syncthreads();
    int k = blockIdx.x * 256 + tid;            // k in [0,768)
    const float4* rowv = (const float4*)(W + (size_t)k * OUT_F);
    float acc1 = 0.f, acc2 = 0.f;
    for (int f4 = 0; f4 < OUT_F / 4; ++f4) {
        float4 w = rowv[f4];
        int f = f4 * 4;
        acc1 += w.x * la[f] + w.y * la[f + 1] + w.z * la[f + 2] + w.w * la[f + 3];
        acc2 += w.x * la[256 + f] + w.y * la[256 + f + 1] + w.z * la[256 + f + 2] + w.w * la[256 + f + 3];
    }
    w1[k] = acc1;
    w2[k] = acc2;
}

// Kernel B: s1[i] = X[i]·w1, s2[i] = X[i]·w2.  One wave per row. grid=2048, block=256
__global__ __launch_bounds__(256) void s1s2_kernel(const float* __restrict__ X,
                                                   const float* __restrict__ w1,
                                                   const float* __restrict__ w2,
                                                   float* __restrict__ s1,
                                                   float* __restrict__ s2) {
    __shared__ float lw[IN_F * 2];
    int tid = threadIdx.x;
    for (int p = tid; p < IN_F; p += 256) { lw[p] = w1[p]; lw[IN_F + p] = w2[p]; }
    __syncthreads();
    int wid = tid >> 6, lane = tid & 63;
    int i = blockIdx.x * 4 + wid;              // i in [0,8192)
    const float4* row = (const float4*)(X + (size_t)i * IN_F);
    const float4* l1  = (const float4*)lw;
    const float4* l2  = (const float4*)(lw + IN_F);
    float a1 = 0.f, a2 = 0.f;
    for (int c = lane; c < IN_F / 4; c += 64) { // 3 iterations
        float4 x = row[c];
        float4 u = l1[c];
        float4 v = l2[c];
        a1 += x.x * u.x + x.y * u.y + x.z * u.z + x.w * u.w;
        a2 += x.x * v.x + x.y * v.y + x.z * v.z + x.w * v.w;
    }
    a1 = waveReduceSum(a1);
    a2 = waveReduceSum(a2);
    if (lane == 0) { s1[i] = a1; s2[i] = a2; }
}

// Kernel C: r[i] += partial row sum of leakyrelu(s1_i + s2_j) over a 1024-wide j chunk.
// leakyrelu(x) = LALPHA*x + (1-LALPHA)*max(x,0); sum of linear part is closed-form.
// grid=(32,8), block=256 (thread -> one i; blockIdx.y -> j chunk)
__global__ __launch_bounds__(256) void rowsum_kernel(const float* __restrict__ s1,
                                                     const float* __restrict__ s2,
                                                     float* __restrict__ r) {
    __shared__ float ls2[1024];
    __shared__ float wsum[4];
    int tid = threadIdx.x;
    int bi = blockIdx.x, bj = blockIdx.y;
    float4 v = ((const float4*)(s2 + bj * 1024))[tid];
    ((float4*)ls2)[tid] = v;
    float lsum = v.x + v.y + v.z + v.w;
    lsum = waveReduceSum(lsum);
    int wid = tid >> 6, lane = tid & 63;
    if (lane == 0) wsum[wid] = lsum;
    __syncthreads();
    float S = wsum[0] + wsum[1] + wsum[2] + wsum[3]; // sum of this s2 chunk
    int i = bi * 256 + tid;
    float s1i = s1[i];
    float accp = 0.f;
    const float4* l4 = (const float4*)ls2;
#pragma unroll 8
    for (int j4 = 0; j4 < 256; ++j4) {
        float4 u = l4[j4];                      // LDS broadcast (all lanes same addr)
        accp += fmaxf(s1i + u.x, 0.f);
        accp += fmaxf(s1i + u.y, 0.f);
        accp += fmaxf(s1i + u.z, 0.f);
        accp += fmaxf(s1i + u.w, 0.f);
    }
    float part = LALPHA * (1024.f * s1i + S) + (1.f - LALPHA) * accp;
    atomicAdd(&r[i], part);
}

// Kernel D: softmax stats over r[8192]; writes att[i]=exp(r[i]-M) and stats={M,Z}.
// grid=1, block=1024
__global__ __launch_bounds__(1024) void softmax_kernel(const float* __restrict__ r,
                                                       float* __restrict__ att,
                                                       float* __restrict__ stats) {
    __shared__ float red[16];
    int t = threadIdx.x;
    int wid = t >> 6, lane = t & 63;
    float vals[8];
    float m = -INFINITY;
    for (int p = 0; p < 8; ++p) {
        vals[p] = r[t + p * 1024];
        m = fmaxf(m, vals[p]);
    }
    m = waveReduceMax(m);
    if (lane == 0) red[wid] = m;
    __syncthreads();
    if (t == 0) {
        float mm = red[0];
        for (int w = 1; w < 16; ++w) mm = fmaxf(mm, red[w]);
        red[0] = mm;
    }
    __syncthreads();
    float M = red[0];
    __syncthreads();                            // everyone has read red[0] before reuse
    float z = 0.f;
    for (int p = 0; p < 8; ++p) {
        float e = expf(vals[p] - M);
        att[t + p * 1024] = e;
        z += e;
    }
    z = waveReduceSum(z);
    if (lane == 0) red[wid] = z;
    __syncthreads();
    if (t == 0) {
        float zz = 0.f;
        for (int w = 0; w < 16; ++w) zz += red[w];
        stats[0] = M;
        stats[1] = zz;
    }
}

// Kernel E: acc768[k] += sum_i att[i] * X[i][k].  Softmax is near-one-hot, so
// att[i]==0 rows (the overwhelming majority) are skipped (wave-uniform branch).
// grid=128, block=256 (each block: 64 rows; thread covers cols tid, tid+256, tid+512)
__global__ __launch_bounds__(256) void wsum_kernel(const float* __restrict__ X,
                                                   const float* __restrict__ att,
                                                   float* __restrict__ acc768) {
    int tid = threadIdx.x;
    int r0 = blockIdx.x * 64;
    float a0 = 0.f, a1 = 0.f, a2 = 0.f;
    for (int i = r0; i < r0 + 64; ++i) {
        float w = att[i];
        if (w != 0.0f) {
            const float* row = X + (size_t)i * IN_F;
            a0 += w * row[tid];
            a1 += w * row[tid + 256];
            a2 += w * row[tid + 512];
        }
    }
    atomicAdd(&acc768[tid], a0);
    atomicAdd(&acc768[tid + 256], a1);
    atomicAdd(&acc768[tid + 512], a2);
}

// Kernel F: out[f] = elu( (acc768 @ W[:,f]) / Z ).  grid=1, block=256
__global__ __launch_bounds__(256) void final_kernel(const float* __restrict__ acc768,
                                                    const float* __restrict__ W,
                                                    const float* __restrict__ stats,
                                                    float* __restrict__ out) {
    int f = threadIdx.x;
    float invZ = 1.0f / stats[1];
    float sum = 0.f;
    for (int k = 0; k < IN_F; ++k)
        sum += acc768[k] * W[(size_t)k * OUT_F + f];   // acc768[k] uniform -> scalar path
    float x = sum * invZ;
    out[f] = (x > 0.f) ? x : (expf(x) - 1.0f);
}

extern "C" void kernel_launch(void* const* d_in, const int* in_sizes, int n_in,
                              void* d_out, int out_size, void* d_ws, size_t ws_size,
                              hipStream_t stream) {
    const float* X = (const float*)d_in[0];   // [8192, 768]
    const float* W = (const float*)d_in[1];   // [768, 256]
    const float* a = (const float*)d_in[2];   // [512, 1]
    float* out = (float*)d_out;               // [256]

    float* ws     = (float*)d_ws;
    float* r      = ws;            // 8192
    float* acc768 = ws + 8192;     // 768
    float* w1     = ws + 8960;     // 768
    float* w2     = ws + 9728;     // 768
    float* s1     = ws + 10496;    // 8192
    float* s2     = ws + 18688;    // 8192
    float* att    = ws + 26880;    // 8192
    float* stats  = ws + 35072;    // 2

    // zero r and acc768 (contiguous) — ws is poisoned before every call
    hipMemsetAsync(r, 0, (8192 + 768) * sizeof(float), stream);

    wvec_kernel<<<3, 256, 0, stream>>>(W, a, w1, w2);
    s1s2_kernel<<<2048, 256, 0, stream>>>(X, w1, w2, s1, s2);
    rowsum_kernel<<<dim3(32, 8), 256, 0, stream>>>(s1, s2, r);
    softmax_kernel<<<1, 1024, 0, stream>>>(r, att, stats);
    wsum_kernel<<<128, 256, 0, stream>>>(X, att, acc768);
    final_kernel<<<1, 256, 0, stream>>>(acc768, W, stats, out);
}